// Round 4
// baseline (337.188 us; speedup 1.0000x reference)
//
#include <hip/hip_runtime.h>
#include <math.h>

#define LL 128
#define TT 11
#define NP 121            // T*T (y, y_prev) pairs
#define KK 7
#define WPB 8             // independent waves (= batches) per block -> 2 waves/SIMD
#define GS 20             // sp group stride (floats): 80 B = 16B-aligned, low bank aliasing
#define SPW 224           // sp floats per wave slice (11*20+10=210 used, dummies at 211..217)

#define LOG2E 1.4426950408889634f
#define LN2   0.6931471805599453f
#define NEG2  (-10000.0f * LOG2E)   // ref NEG in base-2 domain
#define MASK2 (-1.0e9f)             // masked -> exp2 underflows to exactly 0

__device__ __forceinline__ float fast_exp2(float x) { return __builtin_amdgcn_exp2f(x); }
__device__ __forceinline__ float fast_log2(float x) { return __builtin_amdgcn_logf(x); }

// One wave per batch, WPB independent waves per block (private LDS slices, no
// inter-wave sync). Lane l owns pairs o0=l and o1=l+64 (o = y*11 + yp; lanes
// 57..63's second pair is a dummy writing to sp[211..217]). DP runs in base-2
// log domain with a wave-uniform normalizer C (= lane 0's previous alpha2),
// so phase-1 partials are plain pre-scaled sums and phase 2 is adds + one
// log2 per group. Each lane combines BOTH its groups (yp0, yp1) from LDS, so
// both next-step alpha values arrive in-register (no bpermute). LDS ops from
// a single wave complete in order -> only compiler fences (wave_barrier), no
// s_waitcnt: prefetched global loads stay in flight across steps.
__global__ __launch_bounds__(64 * WPB) void hscrf_fwd(const float* __restrict__ scores,
                                                      const int* __restrict__ mask,
                                                      float* __restrict__ out,
                                                      int n_batch)
{
    const int w = threadIdx.x >> 6;
    const int l = threadIdx.x & 63;
    const int b = blockIdx.x * WPB + w;
    if (b >= n_batch) return;

    __shared__ __align__(64) float sp_all[WPB][SPW];
    float* sp = sp_all[w];

    const int o1  = l + 64;
    const int o1c = (o1 < NP) ? o1 : 0;          // clamp for address math only
    const int y0 = l / TT,   yp0 = l % TT;
    const int y1 = o1c / TT, yp1 = o1c % TT;
    const int e0 = yp0 * TT + y0;                // scores pane index [yp][y]
    const int e1 = yp1 * TT + y1;
    const int i0w = y0 * GS + yp0;               // phase-1 write slots
    const int i1w = (o1 < NP) ? (y1 * GS + yp1) : (211 + (l - 57));

    const int mb = mask[b];
    const float* sb = scores + (size_t)b * (size_t)(LL * LL * NP);

    // Sliding alpha2 window: win?[k] = alpha2[i-7+k][yp?] during step i.
    float win0[KK], win1[KK];
#pragma unroll
    for (int k = 0; k < KK; ++k) { win0[k] = MASK2; win1[k] = MASK2; }
    float na0 = (yp0 == TT - 1) ? 0.0f : NEG2;   // alpha2 row 0
    float na1 = (yp1 == TT - 1) ? 0.0f : NEG2;
    float C = 0.0f;                              // wave-uniform normalizer
    float saved = 0.0f;

    // Depth-4 register prefetch of score panes.
    float cA0[KK], cA1[KK], cB0[KK], cB1[KK];
    float cC0[KK], cC1[KK], cD0[KK], cD1[KK];

    auto load_pane = [&](int i, float (&c0)[KK], float (&c1)[KK]) {
#pragma unroll
        for (int k = 0; k < KK; ++k) {
            int j = i - KK + k;
            int jc = j < 0 ? 0 : j;              // clipped like ref; masked via window
            const size_t base = ((size_t)jc * LL + (size_t)(i - 1)) * NP;
            c0[k] = sb[base + e0];
            c1[k] = sb[base + e1];
        }
    };

    load_pane(1, cA0, cA1);
    load_pane(2, cB0, cB1);
    load_pane(3, cC0, cC1);
    load_pane(4, cD0, cD1);

    auto step = [&](int i, float (&c0)[KK], float (&c1)[KK]) {
        // Shift newest alpha2 row into the window (registers only).
#pragma unroll
        for (int k = 0; k < KK - 1; ++k) { win0[k] = win0[k + 1]; win1[k] = win1[k + 1]; }
        win0[KK - 1] = na0;
        win1[KK - 1] = na1;

        // Phase 1: pre-scaled sum over the 7 span starts, both pairs.
        float g0[KK], g1[KK];
#pragma unroll
        for (int k = 0; k < KK; ++k) {
            g0[k] = fast_exp2(fmaf(c0[k], LOG2E, win0[k]) - C);
            g1[k] = fast_exp2(fmaf(c1[k], LOG2E, win1[k]) - C);
        }
        const float s0 = ((g0[0] + g0[1]) + (g0[2] + g0[3])) + ((g0[4] + g0[5]) + g0[6]);
        const float s1 = ((g1[0] + g1[1]) + (g1[2] + g1[3])) + ((g1[4] + g1[5]) + g1[6]);

        sp[i0w] = s0;
        sp[i1w] = s1;

        // Refill this buffer for step i+4 now; loads stay in flight (no
        // vmcnt drain anywhere in the loop).
        if (i + 4 <= LL) load_pane(i + 4, c0, c1);

        __builtin_amdgcn_wave_barrier();   // compiler fence; LDS pipe is in-order per wave

        // Phase 2: combine both groups (11 contiguous floats each, b128-aligned).
        const float4 r0a = *(const float4*)(sp + yp0 * GS);
        const float4 r0b = *(const float4*)(sp + yp0 * GS + 4);
        const float2 r0c = *(const float2*)(sp + yp0 * GS + 8);
        const float  r0d = sp[yp0 * GS + 10];
        const float4 r1a = *(const float4*)(sp + yp1 * GS);
        const float4 r1b = *(const float4*)(sp + yp1 * GS + 4);
        const float2 r1c = *(const float2*)(sp + yp1 * GS + 8);
        const float  r1d = sp[yp1 * GS + 10];

        const float S0 = (((r0a.x + r0a.y) + (r0a.z + r0a.w)) +
                          ((r0b.x + r0b.y) + (r0b.z + r0b.w))) +
                         ((r0c.x + r0c.y) + r0d);
        const float S1 = (((r1a.x + r1a.y) + (r1a.z + r1a.w)) +
                          ((r1b.x + r1b.y) + (r1b.z + r1b.w))) +
                         ((r1c.x + r1c.y) + r1d);

        const float A0 = C + fast_log2(S0);      // alpha2[i][yp0]
        const float A1 = C + fast_log2(S1);      // alpha2[i][yp1]
        na0 = A0;
        na1 = A1;
        saved = (i == mb) ? A0 : saved;
        // Lane 0 has yp0 == 0 -> C becomes alpha2[i][0], uniform.
        C = __int_as_float(__builtin_amdgcn_readfirstlane(__float_as_int(A0)));

        __builtin_amdgcn_wave_barrier();   // order phase-2 reads before next writes
    };

    for (int i = 1; i <= LL; i += 4) {
        step(i,     cA0, cA1);
        step(i + 1, cB0, cB1);
        step(i + 2, cC0, cC1);
        step(i + 3, cD0, cD1);
    }

    if (l == TT - 2) {                           // lane 9: yp0 == stop_id
        atomicAdd(out, saved * LN2);             // back to natural log
    }
}

extern "C" void kernel_launch(void* const* d_in, const int* in_sizes, int n_in,
                              void* d_out, int out_size, void* d_ws, size_t ws_size,
                              hipStream_t stream) {
    const float* scores = (const float*)d_in[0];
    const int*   mask   = (const int*)d_in[1];
    float* out = (float*)d_out;
    const int B = in_sizes[1];   // 16

    hipMemsetAsync(out, 0, sizeof(float) * out_size, stream);
    hscrf_fwd<<<(B + WPB - 1) / WPB, 64 * WPB, 0, stream>>>(scores, mask, out, B);
}

// Round 5
// 227.601 us; speedup vs baseline: 1.4815x; 1.4815x over previous
//
#include <hip/hip_runtime.h>
#include <math.h>

#define LL 128
#define TT 11
#define NP 121            // T*T (y, y_prev) pairs
#define KK 7
#define GS 20             // sp group stride (floats); group g at [g*20 .. g*20+10], pad at +11
#define SPW 240           // 11 groups*20 + dummy slots 220..226

#define LOG2E 1.4426950408889634f
#define LN2   0.6931471805599453f
#define NEG2  (-10000.0f * LOG2E)   // ref NEG in base-2 domain
#define MASK2 (-1.0e9f)             // masked -> exp2 underflows to exactly 0

__device__ __forceinline__ float fast_exp2(float x) { return __builtin_amdgcn_exp2f(x); }
__device__ __forceinline__ float fast_log2(float x) { return __builtin_amdgcn_logf(x); }
__device__ __forceinline__ float rfl(float x) {
    return __int_as_float(__builtin_amdgcn_readfirstlane(__float_as_int(x)));
}

// ONE WAVE PER CU (16 blocks x 64 threads): the DP is a serial latency chain;
// any sharing of the DS/trans/VALU pipes doubles step time (round-4 evidence).
//
// Lane l owns pairs o0=l, o1=l+64 (o = y*11 + yp; lanes 57..63's second pair
// is a dummy writing to sp[220..226]). Base-2 log domain with wave-uniform
// normalizer C pipelined 2 steps back (C_i = alpha2[i-2][0] via
// readfirstlane), so the 6 older phase-1 terms (pp) are computed one step
// EARLY inside the LDS-read latency shadow; only ONE exp2 (the alpha[i-1]
// term) sits on the serial chain. Phase 2: each lane sums group yp (== its
// own y_prev), 3x b128 reads with a zeroed pad slot, so next-step alpha
// arrives in-register. LDS ops of a single wave complete in order -> only
// compiler fences (wave_barrier), never s_waitcnt: prefetched global score
// loads stay in flight across steps.
__global__ __launch_bounds__(64) void hscrf_fwd(const float* __restrict__ scores,
                                                const int* __restrict__ mask,
                                                float* __restrict__ out,
                                                int n_batch)
{
    const int l = threadIdx.x;
    const int b = blockIdx.x;
    if (b >= n_batch) return;

    __shared__ __align__(64) float sp[SPW];

    const int o1  = l + 64;
    const int o1c = (o1 < NP) ? o1 : 0;          // clamp for address math only
    const int y0 = l / TT,   yp0 = l % TT;
    const int y1 = o1c / TT, yp1 = o1c % TT;
    const int e0 = yp0 * TT + y0;                // scores pane index [yp][y]
    const int e1 = yp1 * TT + y1;
    const int i0w = y0 * GS + yp0;               // phase-1 write slots
    const int i1w = (o1 < NP) ? (y1 * GS + yp1) : (220 + (l - 57));

    // Zero the pad slot (element 11) of each group so phase-2 can read 3xb128.
    if (l < TT) sp[l * GS + 11] = 0.0f;

    const int mb = mask[b];
    const float* sb = scores + (size_t)b * (size_t)(LL * LL * NP);

    // Sliding alpha2 window: win?[k] = alpha2[i-7+k][yp?] during step i.
    float win0[KK], win1[KK];
#pragma unroll
    for (int k = 0; k < KK; ++k) { win0[k] = MASK2; win1[k] = MASK2; }
    float na0 = (yp0 == TT - 1) ? 0.0f : NEG2;   // alpha2 row 0 (start_id = 10)
    float na1 = (yp1 == TT - 1) ? 0.0f : NEG2;

    float C  = 0.0f;   // normalizer for current step  (C_i   = alpha2[i-2][0])
    float Cn = 0.0f;   // normalizer for next step     (C_i+1 = alpha2[i-1][0])
    float pp0 = 0.0f, pp1 = 0.0f;   // 6-older-term partials for the current step
    float saved = 0.0f;

    // Depth-4 register prefetch of score panes (pane i = scores[j][i-1][:][:],
    // j = i-7..i-1).
    float cA0[KK], cA1[KK], cB0[KK], cB1[KK];
    float cC0[KK], cC1[KK], cD0[KK], cD1[KK];

    auto load_pane = [&](int i, float (&c0)[KK], float (&c1)[KK]) {
#pragma unroll
        for (int k = 0; k < KK; ++k) {
            int j = i - KK + k;
            int jc = j < 0 ? 0 : j;              // clipped like ref; masked via window
            const size_t base = ((size_t)jc * LL + (size_t)(i - 1)) * NP;
            c0[k] = sb[base + e0];
            c1[k] = sb[base + e1];
        }
    };

    load_pane(1, cA0, cA1);
    load_pane(2, cB0, cB1);
    load_pane(3, cC0, cC1);
    load_pane(4, cD0, cD1);

    // c = panes for step i (refilled for i+4), n = panes for step i+1 (read-only here).
    auto step = [&](int i, float (&c0)[KK], float (&c1)[KK],
                    float (&n0)[KK], float (&n1)[KK]) {
        // Shift newest alpha2 row into the window (registers only).
#pragma unroll
        for (int k = 0; k < KK - 1; ++k) { win0[k] = win0[k + 1]; win1[k] = win1[k + 1]; }
        win0[KK - 1] = na0;
        win1[KK - 1] = na1;

        // CHAIN: the single alpha[i-1]-dependent term, then the pre-built partial.
        const float g0 = fast_exp2(fmaf(c0[KK - 1], LOG2E, win0[KK - 1]) - C);
        const float g1 = fast_exp2(fmaf(c1[KK - 1], LOG2E, win1[KK - 1]) - C);
        sp[i0w] = pp0 + g0;
        sp[i1w] = pp1 + g1;

        // Refill this pane for step i+4; loads stay in flight (no vmcnt drain).
        if (i + 4 <= LL) load_pane(i + 4, c0, c1);

        __builtin_amdgcn_wave_barrier();   // compiler fence; DS pipe in-order per wave

        // Phase-2 reads issued first so their ~120-cyc latency overlaps the
        // off-chain pp computation below.
        const float4 qa0 = *(const float4*)(sp + yp0 * GS);
        const float4 qb0 = *(const float4*)(sp + yp0 * GS + 4);
        const float4 qc0 = *(const float4*)(sp + yp0 * GS + 8);   // [8..11], pad=0
        const float4 qa1 = *(const float4*)(sp + yp1 * GS);
        const float4 qb1 = *(const float4*)(sp + yp1 * GS + 4);
        const float4 qc1 = *(const float4*)(sp + yp1 * GS + 8);

        // OFF-CHAIN: 6 older terms of step i+1 (uses alpha2[i-6..i-1] =
        // win[1..6], pane n, normalizer Cn = alpha2[i-1][0]).
        float t0 = 0.0f, t1 = 0.0f;
#pragma unroll
        for (int k = 0; k < KK - 1; ++k) {
            t0 += fast_exp2(fmaf(n0[k], LOG2E, win0[k + 1]) - Cn);
            t1 += fast_exp2(fmaf(n1[k], LOG2E, win1[k + 1]) - Cn);
        }
        pp0 = t0;
        pp1 = t1;

        // Phase-2 sums (12 values incl. zero pad).
        const float S0 = (((qa0.x + qa0.y) + (qa0.z + qa0.w)) +
                          ((qb0.x + qb0.y) + (qb0.z + qb0.w))) +
                         ((qc0.x + qc0.y) + (qc0.z + qc0.w));
        const float S1 = (((qa1.x + qa1.y) + (qa1.z + qa1.w)) +
                          ((qb1.x + qb1.y) + (qb1.z + qb1.w))) +
                         ((qc1.x + qc1.y) + (qc1.z + qc1.w));

        const float A0 = C + fast_log2(S0);      // alpha2[i][yp0]
        const float A1 = C + fast_log2(S1);      // alpha2[i][yp1]
        na0 = A0;
        na1 = A1;
        saved = (i == mb) ? A0 : saved;

        // Normalizer pipeline: lane 0 has yp0==0, so rfl(A0) = alpha2[i][0].
        C  = Cn;
        Cn = rfl(A0);

        __builtin_amdgcn_wave_barrier();   // order phase-2 reads before next writes
    };

    for (int i = 1; i <= LL; i += 4) {
        step(i,     cA0, cA1, cB0, cB1);
        step(i + 1, cB0, cB1, cC0, cC1);
        step(i + 2, cC0, cC1, cD0, cD1);
        step(i + 3, cD0, cD1, cA0, cA1);
    }

    if (l == TT - 2) {                           // lane 9: yp0 == stop_id = 9
        atomicAdd(out, saved * LN2);             // back to natural log
    }
}

extern "C" void kernel_launch(void* const* d_in, const int* in_sizes, int n_in,
                              void* d_out, int out_size, void* d_ws, size_t ws_size,
                              hipStream_t stream) {
    const float* scores = (const float*)d_in[0];
    const int*   mask   = (const int*)d_in[1];
    float* out = (float*)d_out;
    const int B = in_sizes[1];   // 16

    hipMemsetAsync(out, 0, sizeof(float) * out_size, stream);
    hscrf_fwd<<<B, 64, 0, stream>>>(scores, mask, out, B);   // one wave per CU
}